// Round 1
// baseline (605.514 us; speedup 1.0000x reference)
//
#include <hip/hip_runtime.h>
#include <hip/hip_bf16.h>
#include <math.h>

#define BB 16
#define CC 64
#define NN 512
#define TT 128
#define JJ (NN*TT)   // 65536 columns per (b, channel) in the mix view
#define JT 128       // j-tile for mix kernel
#define KP 129       // padded row stride for k tile (conflict-free stride-TT reads)
#define AP 68        // padded [i][c] stride for attT: 4-aligned (float4 reads ok),
                     // 68%32=4 -> transposed scalar stores spread over 8 banks

// ---------------------------------------------------------------------------
// K1: k[b,c,t] = sum_i sig[b,c,i,t] * alpha[i]
// one block per (b,c); 256 threads = 8 i-subgroups x 32 t-quads (float4)
// ---------------------------------------------------------------------------
__global__ __launch_bounds__(256) void k_reduce_kernel(
    const float* __restrict__ sig, const float* __restrict__ alpha,
    float* __restrict__ kout)
{
    __shared__ float aS[NN];
    __shared__ float4 red[8][32];
    const int tid = threadIdx.x;
    for (int x = tid; x < NN; x += 256) aS[x] = alpha[x];
    __syncthreads();

    const int bc = blockIdx.x;
    const float* base = sig + (size_t)bc * (NN * TT);
    const int t4 = tid & 31;   // which float4 of the T=128 row
    const int ig = tid >> 5;   // i-subgroup 0..7

    float4 acc = make_float4(0.f, 0.f, 0.f, 0.f);
    for (int i = ig; i < NN; i += 8) {
        float4 v = *(const float4*)(base + i * TT + t4 * 4);
        const float a = aS[i];
        acc.x = fmaf(v.x, a, acc.x);
        acc.y = fmaf(v.y, a, acc.y);
        acc.z = fmaf(v.z, a, acc.z);
        acc.w = fmaf(v.w, a, acc.w);
    }
    red[ig][t4] = acc;
    __syncthreads();
    if (tid < 32) {
        float4 s = red[0][tid];
        #pragma unroll
        for (int g = 1; g < 8; g++) {
            float4 r = red[g][tid];
            s.x += r.x; s.y += r.y; s.z += r.z; s.w += r.w;
        }
        *(float4*)(kout + (size_t)bc * TT + tid * 4) = s;
    }
}

// ---------------------------------------------------------------------------
// K2 (fused): per (b,c) block:
//   tmp[s]  = sum_t k[b,c,t] * Wc[t,s]          (threads 0..127)
//   sc[d]   = sum_s tmp[s] * k[b,d,s]           (threads 0..63)
//   att[b,c,:] = softmax(sc)                    (wave-0 shuffle reduction)
// grid = B*C = 1024 blocks -> full-device parallelism for the tiny stage.
// ---------------------------------------------------------------------------
__global__ __launch_bounds__(256) void attn_fused_kernel(
    const float* __restrict__ kin, const float* __restrict__ Wc,
    float* __restrict__ att)
{
    __shared__ float kAll[CC * KP];   // k[b] tile, rows padded to 129
    __shared__ float tmp[TT];
    const int tid = threadIdx.x;
    const int b = blockIdx.x >> 6;
    const int c = blockIdx.x & 63;

    const float* kb = kin + b * CC * TT;
    for (int x = tid; x < CC * TT; x += 256)
        kAll[(x >> 7) * KP + (x & 127)] = kb[x];   // coalesced read, seq-bank write
    __syncthreads();

    if (tid < TT) {
        float acc = 0.f;
        const float* kc = &kAll[c * KP];           // wave-uniform -> LDS broadcast
        for (int t = 0; t < TT; t++)
            acc = fmaf(kc[t], Wc[t * TT + tid], acc);  // Wc coalesced per wave
        tmp[tid] = acc;
    }
    __syncthreads();

    if (tid < CC) {                                // exactly wave 0
        float acc = 0.f;
        const float* kd = &kAll[tid * KP];         // stride 129 -> 2-way (free)
        for (int s = 0; s < TT; s++)
            acc = fmaf(tmp[s], kd[s], acc);        // tmp broadcast

        float m = acc;
        #pragma unroll
        for (int off = 32; off >= 1; off >>= 1)
            m = fmaxf(m, __shfl_xor(m, off, 64));
        const float e = __expf(acc - m);
        float sum = e;
        #pragma unroll
        for (int off = 32; off >= 1; off >>= 1)
            sum += __shfl_xor(sum, off, 64);
        att[b * CC * CC + c * CC + tid] = e / sum;
    }
}

// ---------------------------------------------------------------------------
// K3: out[b][c][j] = sum_i att[b][c][i] * sig[b][i][j],  j = n*T + t flattened
// grid = (JJ/JT, B); block 128 (2 waves). LDS: attT[i][c] padded to AP=68
// (transpose store spreads 8 banks; float4 reads stay conflict-free) + sig
// tile 64xJT. Each thread: 8c x 8j register tile (64 accumulators) ->
// 4 ds_read_b128 per i for 64 MACs = 1.0 B/MAC LDS traffic (was 1.5).
// ---------------------------------------------------------------------------
__global__ __launch_bounds__(128) void mix_kernel(
    const float* __restrict__ sig, const float* __restrict__ att,
    float* __restrict__ out)
{
    __shared__ float attT[CC * AP];      // [i][c] padded, 17 KiB
    __shared__ float stile[CC][JT];      // 32 KiB
    const int b = blockIdx.y;
    const int jbase = blockIdx.x * JT;
    const int tid = threadIdx.x;

    const float* ab = att + b * CC * CC;
    for (int x = tid; x < CC * CC; x += 128) {
        const int c = x >> 6;            // wave-uniform
        const int i = x & 63;            // = lane
        attT[i * AP + c] = ab[x];        // coalesced read; 8-bank spread store
    }

    const float* sb = sig + (size_t)b * CC * JJ + jbase;
    for (int x = tid; x < CC * JT / 4; x += 128) {
        const int i = x >> 5;   // JT/4 = 32 quads per row
        const int q = x & 31;
        *(float4*)(&stile[i][q * 4]) = *(const float4*)(sb + (size_t)i * JJ + q * 4);
    }
    __syncthreads();

    const int tc = tid >> 4;   // 0..7 -> channels 8*tc .. 8*tc+7
    const int tj = tid & 15;   // quads tj and tj+16

    float4 acc[8][2];
    #pragma unroll
    for (int q = 0; q < 8; q++) {
        acc[q][0] = make_float4(0.f, 0.f, 0.f, 0.f);
        acc[q][1] = make_float4(0.f, 0.f, 0.f, 0.f);
    }

    #pragma unroll 4
    for (int i = 0; i < CC; i++) {
        const float4 a0 = *(const float4*)(&attT[i * AP + 8 * tc]);      // 1 b128
        const float4 a1 = *(const float4*)(&attT[i * AP + 8 * tc + 4]);  // 1 b128
        const float a[8] = {a0.x, a0.y, a0.z, a0.w, a1.x, a1.y, a1.z, a1.w};
        const float4 s0 = *(const float4*)(&stile[i][tj * 4]);
        const float4 s1 = *(const float4*)(&stile[i][(tj + 16) * 4]);
        #pragma unroll
        for (int q = 0; q < 8; q++) {
            acc[q][0].x = fmaf(a[q], s0.x, acc[q][0].x);
            acc[q][0].y = fmaf(a[q], s0.y, acc[q][0].y);
            acc[q][0].z = fmaf(a[q], s0.z, acc[q][0].z);
            acc[q][0].w = fmaf(a[q], s0.w, acc[q][0].w);
            acc[q][1].x = fmaf(a[q], s1.x, acc[q][1].x);
            acc[q][1].y = fmaf(a[q], s1.y, acc[q][1].y);
            acc[q][1].z = fmaf(a[q], s1.z, acc[q][1].z);
            acc[q][1].w = fmaf(a[q], s1.w, acc[q][1].w);
        }
    }

    float* ob = out + (size_t)b * CC * JJ + jbase;
    #pragma unroll
    for (int q = 0; q < 8; q++) {
        const int c = 8 * tc + q;
        #pragma unroll
        for (int u = 0; u < 2; u++)
            *(float4*)(ob + (size_t)c * JJ + (tj + 16 * u) * 4) = acc[q][u];
    }
}

// ---------------------------------------------------------------------------
extern "C" void kernel_launch(void* const* d_in, const int* in_sizes, int n_in,
                              void* d_out, int out_size, void* d_ws, size_t ws_size,
                              hipStream_t stream) {
    const float* sig   = (const float*)d_in[0];  // [B,C,N,T]
    const float* Wc    = (const float*)d_in[1];  // [T,T]
    const float* alpha = (const float*)d_in[2];  // [N]
    float* out = (float*)d_out;

    float* k   = (float*)d_ws;            // B*C*T = 131072 floats
    float* att = k + BB * CC * TT;        // B*C*C = 65536 floats

    k_reduce_kernel<<<BB * CC, 256, 0, stream>>>(sig, alpha, k);
    attn_fused_kernel<<<BB * CC, 256, 0, stream>>>(k, Wc, att);
    mix_kernel<<<dim3(JJ / JT, BB), 128, 0, stream>>>(sig, att, out);
}

// Round 2
// 533.448 us; speedup vs baseline: 1.1351x; 1.1351x over previous
//
#include <hip/hip_runtime.h>
#include <hip/hip_bf16.h>
#include <math.h>

#define BB 16
#define CC 64
#define NN 512
#define TT 128
#define JJ (NN*TT)   // 65536 columns per (b, channel) in the mix view
#define JT 256       // j-tile for mix kernel (256 threads x 64 out/thread)
#define IH 32        // i-half: stile staged in two 32-row chunks
#define KP 129       // padded row stride for k tile (conflict-free stride-TT reads)
#define AP 68        // padded [i][c] stride for attT: 4-aligned (float4 reads ok),
                     // 68%32=4 -> transposed scalar stores spread over 8 banks

// ---------------------------------------------------------------------------
// K1: k[b,c,t] = sum_i sig[b,c,i,t] * alpha[i]
// one block per (b,c); 256 threads = 8 i-subgroups x 32 t-quads (float4)
// ---------------------------------------------------------------------------
__global__ __launch_bounds__(256) void k_reduce_kernel(
    const float* __restrict__ sig, const float* __restrict__ alpha,
    float* __restrict__ kout)
{
    __shared__ float aS[NN];
    __shared__ float4 red[8][32];
    const int tid = threadIdx.x;
    for (int x = tid; x < NN; x += 256) aS[x] = alpha[x];
    __syncthreads();

    const int bc = blockIdx.x;
    const float* base = sig + (size_t)bc * (NN * TT);
    const int t4 = tid & 31;   // which float4 of the T=128 row
    const int ig = tid >> 5;   // i-subgroup 0..7

    float4 acc = make_float4(0.f, 0.f, 0.f, 0.f);
    for (int i = ig; i < NN; i += 8) {
        float4 v = *(const float4*)(base + i * TT + t4 * 4);
        const float a = aS[i];
        acc.x = fmaf(v.x, a, acc.x);
        acc.y = fmaf(v.y, a, acc.y);
        acc.z = fmaf(v.z, a, acc.z);
        acc.w = fmaf(v.w, a, acc.w);
    }
    red[ig][t4] = acc;
    __syncthreads();
    if (tid < 32) {
        float4 s = red[0][tid];
        #pragma unroll
        for (int g = 1; g < 8; g++) {
            float4 r = red[g][tid];
            s.x += r.x; s.y += r.y; s.z += r.z; s.w += r.w;
        }
        *(float4*)(kout + (size_t)bc * TT + tid * 4) = s;
    }
}

// ---------------------------------------------------------------------------
// K2 (fused): per (b,c) block:
//   tmp[s]  = sum_t k[b,c,t] * Wc[t,s]          (threads 0..127)
//   sc[d]   = sum_s tmp[s] * k[b,d,s]           (threads 0..63)
//   att[b,c,:] = softmax(sc)                    (wave-0 shuffle reduction)
// ---------------------------------------------------------------------------
__global__ __launch_bounds__(256) void attn_fused_kernel(
    const float* __restrict__ kin, const float* __restrict__ Wc,
    float* __restrict__ att)
{
    __shared__ float kAll[CC * KP];   // k[b] tile, rows padded to 129
    __shared__ float tmp[TT];
    const int tid = threadIdx.x;
    const int b = blockIdx.x >> 6;
    const int c = blockIdx.x & 63;

    const float* kb = kin + b * CC * TT;
    for (int x = tid; x < CC * TT; x += 256)
        kAll[(x >> 7) * KP + (x & 127)] = kb[x];   // coalesced read, seq-bank write
    __syncthreads();

    if (tid < TT) {
        float acc = 0.f;
        const float* kc = &kAll[c * KP];           // wave-uniform -> LDS broadcast
        for (int t = 0; t < TT; t++)
            acc = fmaf(kc[t], Wc[t * TT + tid], acc);  // Wc coalesced per wave
        tmp[tid] = acc;
    }
    __syncthreads();

    if (tid < CC) {                                // exactly wave 0
        float acc = 0.f;
        const float* kd = &kAll[tid * KP];         // stride 129 -> 2-way (free)
        for (int s = 0; s < TT; s++)
            acc = fmaf(tmp[s], kd[s], acc);        // tmp broadcast

        float m = acc;
        #pragma unroll
        for (int off = 32; off >= 1; off >>= 1)
            m = fmaxf(m, __shfl_xor(m, off, 64));
        const float e = __expf(acc - m);
        float sum = e;
        #pragma unroll
        for (int off = 32; off >= 1; off >>= 1)
            sum += __shfl_xor(sum, off, 64);
        att[b * CC * CC + c * CC + tid] = e / sum;
    }
}

// ---------------------------------------------------------------------------
// K3: out[b][c][j] = sum_i att[b][c][i] * sig[b][i][j],  j = n*T + t flattened
// grid = (JJ/JT, B); block 256 (4 waves). Tile: 64c x 256j, i split in two
// 32-row halves so stile fits 32 KiB -> LDS 50 KiB -> 3 blocks/CU = 12
// waves/CU (the occupancy regime that ran 48% VALUBusy in round 0).
// Each thread: 8c x 8j register tile; per i: 2 b128 att + 2 b128 stile
// = 64 B per 64 FMAs = 1.0 B/MAC LDS traffic (pipe floor ~82 us).
// ---------------------------------------------------------------------------
__global__ __launch_bounds__(256) void mix_kernel(
    const float* __restrict__ sig, const float* __restrict__ att,
    float* __restrict__ out)
{
    __shared__ float attT[CC * AP];      // [i][c] padded, 17 KiB
    __shared__ float stile[IH][JT];      // 32 KiB
    const int b = blockIdx.y;
    const int jbase = blockIdx.x * JT;
    const int tid = threadIdx.x;

    const float* ab = att + b * CC * CC;
    for (int x = tid; x < CC * CC; x += 256) {
        const int c = x >> 6;            // row of att
        const int i = x & 63;            // = lane -> coalesced global read
        attT[i * AP + c] = ab[x];        // 8-bank-spread transposed store
    }

    const float* sb = sig + (size_t)b * CC * JJ + jbase;

    const int tc = tid >> 5;   // 0..7 -> channels 8*tc .. 8*tc+7
    const int tj = tid & 31;   // quads tj and tj+32 (of 64 quads = 256 j)

    float4 acc[8][2];
    #pragma unroll
    for (int q = 0; q < 8; q++) {
        acc[q][0] = make_float4(0.f, 0.f, 0.f, 0.f);
        acc[q][1] = make_float4(0.f, 0.f, 0.f, 0.f);
    }

    #pragma unroll
    for (int h = 0; h < 2; h++) {
        // stage rows [32h, 32h+32) of the sig tile: 2048 float4, 8/thread
        for (int x = tid; x < IH * JT / 4; x += 256) {
            const int il = x >> 6;   // local row 0..31
            const int q = x & 63;    // quad
            *(float4*)(&stile[il][q * 4]) =
                *(const float4*)(sb + (size_t)(h * IH + il) * JJ + q * 4);
        }
        __syncthreads();

        #pragma unroll 4
        for (int il = 0; il < IH; il++) {
            const int i = h * IH + il;
            const float4 a0 = *(const float4*)(&attT[i * AP + 8 * tc]);
            const float4 a1 = *(const float4*)(&attT[i * AP + 8 * tc + 4]);
            const float a[8] = {a0.x, a0.y, a0.z, a0.w, a1.x, a1.y, a1.z, a1.w};
            const float4 s0 = *(const float4*)(&stile[il][tj * 4]);
            const float4 s1 = *(const float4*)(&stile[il][(tj + 32) * 4]);
            #pragma unroll
            for (int q = 0; q < 8; q++) {
                acc[q][0].x = fmaf(a[q], s0.x, acc[q][0].x);
                acc[q][0].y = fmaf(a[q], s0.y, acc[q][0].y);
                acc[q][0].z = fmaf(a[q], s0.z, acc[q][0].z);
                acc[q][0].w = fmaf(a[q], s0.w, acc[q][0].w);
                acc[q][1].x = fmaf(a[q], s1.x, acc[q][1].x);
                acc[q][1].y = fmaf(a[q], s1.y, acc[q][1].y);
                acc[q][1].z = fmaf(a[q], s1.z, acc[q][1].z);
                acc[q][1].w = fmaf(a[q], s1.w, acc[q][1].w);
            }
        }
        __syncthreads();   // guard stile overwrite by next half
    }

    float* ob = out + (size_t)b * CC * JJ + jbase;
    #pragma unroll
    for (int q = 0; q < 8; q++) {
        const int c = 8 * tc + q;
        #pragma unroll
        for (int u = 0; u < 2; u++)
            *(float4*)(ob + (size_t)c * JJ + (tj + 32 * u) * 4) = acc[q][u];
    }
}

// ---------------------------------------------------------------------------
extern "C" void kernel_launch(void* const* d_in, const int* in_sizes, int n_in,
                              void* d_out, int out_size, void* d_ws, size_t ws_size,
                              hipStream_t stream) {
    const float* sig   = (const float*)d_in[0];  // [B,C,N,T]
    const float* Wc    = (const float*)d_in[1];  // [T,T]
    const float* alpha = (const float*)d_in[2];  // [N]
    float* out = (float*)d_out;

    float* k   = (float*)d_ws;            // B*C*T = 131072 floats
    float* att = k + BB * CC * TT;        // B*C*C = 65536 floats

    k_reduce_kernel<<<BB * CC, 256, 0, stream>>>(sig, alpha, k);
    attn_fused_kernel<<<BB * CC, 256, 0, stream>>>(k, Wc, att);
    mix_kernel<<<dim3(JJ / JT, BB), 256, 0, stream>>>(sig, att, out);
}